// Round 21
// baseline (193.235 us; speedup 1.0000x reference)
//
#include <hip/hip_runtime.h>

typedef unsigned short u16;
typedef unsigned int u32;
typedef _Float16 f16;
typedef __attribute__((ext_vector_type(8))) _Float16 f16x8;
typedef __attribute__((ext_vector_type(4))) float f32x4;
typedef __attribute__((ext_vector_type(4))) u32 u32x4;
typedef __attribute__((ext_vector_type(2))) u32 u32x2;
typedef __attribute__((ext_vector_type(4))) u16 u16x4;

static __device__ __forceinline__ u16 f16r(float f) {  // RNE f32->f16 bits
  return __builtin_bit_cast(u16, (_Float16)f);
}
static __device__ __forceinline__ u32 packh(float a, float b) {  // v_cvt_pkrtz_f16_f32
  return __builtin_bit_cast(u32, __builtin_amdgcn_cvt_pkrtz(a, b));
}
// async global->LDS, 16B/lane; LDS dst = wave-uniform base + lane*16 (HW), global src per-lane
static __device__ __forceinline__ void gload16(const u16* g, u16* l) {
  __builtin_amdgcn_global_load_lds((const __attribute__((address_space(1))) void*)g,
                                   (__attribute__((address_space(3))) void*)l, 16, 0, 0);
}

// ============ fused weight transpose: W[k][n] fp32 -> pre-tiled/swizzled f16 ============
// WT layout: [nt(8)][kt32(32)][row(128)][pc(4)][8 u16], pc = lc ^ ((row>>1)&3), lc = (k&31)>>3
__global__ __launch_bounds__(256) void wtrans4_k(
    const float* __restrict__ Wq, const float* __restrict__ Wk,
    const float* __restrict__ Wv, const float* __restrict__ Wo,
    u16* __restrict__ Tq, u16* __restrict__ Tk, u16* __restrict__ Tv, u16* __restrict__ To) {
  int z = blockIdx.z;
  const float* W = z == 0 ? Wq : z == 1 ? Wk : z == 2 ? Wv : Wo;
  u16* WT = z == 0 ? Tq : z == 1 ? Tk : z == 2 ? Tv : To;
  __shared__ float tile[32][33];
  int k0 = blockIdx.x * 32, n0 = blockIdx.y * 32;
  int t = threadIdx.x;
  int r = t >> 3, c = (t & 7) * 4;
  f32x4 v = *(const f32x4*)&W[(size_t)(k0 + r) * 1024 + n0 + c];
  tile[r][c + 0] = v[0]; tile[r][c + 1] = v[1]; tile[r][c + 2] = v[2]; tile[r][c + 3] = v[3];
  __syncthreads();
  int n = n0 + (t >> 3), kbase = k0 + (t & 7) * 4;
  u16x4 o;
#pragma unroll
  for (int j = 0; j < 4; j++) o[j] = f16r(tile[(t & 7) * 4 + j][t >> 3]);
  int nt = n >> 7, row = n & 127;
  int kt = kbase >> 5, lc = (kbase >> 3) & 3, e = kbase & 7;
  int pc = lc ^ ((row >> 1) & 3);
  *(u16x4*)&WT[((size_t)(nt * 32 + kt) * 128 + row) * 32 + pc * 8 + e] = o;
}

// ============ fused Q/K/V projection GEMM: BK=32, 3-DEEP ring, REG-STAGED f16 A ====
// A: plain f32x4 loads (tile t+3, issued after end-barrier, held in regs ra[3][4]) ->
// cvt_pkrtz -> ds_write into f16 As[3][4096]. B: linear gload_lds into Bs[3][4096].
// LDS 48KB -> still 3 blocks/CU (R16's 3-deep failed only because fp32 As cost 72KB).
// vmcnt ring: 6 ops/stage, 3 stages -> steady wait vmcnt(12) (~2 iters ~ HBM latency).
// Epilogue: LDS-bounce -> two contiguous 16KB coalesced store runs.
__global__ __launch_bounds__(256) void gemm_qkv_k(
    const float* __restrict__ Aq, const float* __restrict__ Ak, const float* __restrict__ Av,
    const u16* __restrict__ Tq, const u16* __restrict__ Tk, const u16* __restrict__ Tv,
    const float* __restrict__ bq, const float* __restrict__ bk, const float* __restrict__ bv,
    u16* __restrict__ Qo, u16* __restrict__ Ko, u16* __restrict__ Vo, float qscale) {
  int z = blockIdx.z;
  const float* A = z == 0 ? Aq : z == 1 ? Ak : Av;
  const u16* BT = z == 0 ? Tq : z == 1 ? Tk : Tv;
  const float* bias = z == 0 ? bq : z == 1 ? bk : bv;
  u16* out = z == 0 ? Qo : z == 1 ? Ko : Vo;
  int vmode = (z == 2);
  float scale = z == 0 ? qscale : 1.0f;

  __shared__ u16 SH[24576];  // As[3][4096] | Bs[3][4096] during K-loop; C tile in epilogue
  u16 (*As)[4096] = (u16(*)[4096])SH;
  u16 (*Bs)[4096] = (u16(*)[4096])(SH + 12288);
  int lid = blockIdx.x;
  int xcd = lid & 7, idx = lid >> 3;
  int bx = idx & 7, by = xcd * 8 + (idx >> 3);
  int n0 = bx * 128, m0 = by * 128;
  int tid = threadIdx.x, lane = tid & 63;
  int w = tid >> 6, wr = w >> 1, wc = w & 1;
  int fq = lane & 15, fc = lane >> 4;
  f32x4 acc[4][4] = {};
  const u16* BTb = BT + (size_t)bx * 131072;
  const float* Ab = A + (size_t)m0 * 1024;

  // A staging geometry: unit = (row, lc); thread handles (arow0, lc) and (arow0+64, lc)
  int arow0 = tid >> 2;          // 0..63
  int arow1 = arow0 + 64;
  int acol = (tid & 3) * 8;      // float col within the 32-float K slab
  int apc = (tid & 3) ^ ((arow0 >> 1) & 3);  // same for arow1 (+64 preserves (row>>1)&3)
  int aw0 = arow0 * 32 + apc * 8;
  int aw1 = arow1 * 32 + apc * 8;
  f32x4 ra[3][4];

#define QKV_LOAD_A(KS, S)                                                       \
  {                                                                             \
    const float* Ap = Ab + (KS) * 32 + acol;                                    \
    ra[S][0] = *(const f32x4*)(Ap + (size_t)arow0 * 1024);                      \
    ra[S][1] = *(const f32x4*)(Ap + (size_t)arow0 * 1024 + 4);                  \
    ra[S][2] = *(const f32x4*)(Ap + (size_t)arow1 * 1024);                      \
    ra[S][3] = *(const f32x4*)(Ap + (size_t)arow1 * 1024 + 4);                  \
  }
#define QKV_LOAD_B(KS, S)                                                       \
  {                                                                             \
    const u16* Bt = BTb + (KS) * 4096;                                          \
    gload16(Bt + (w * 2 + 0) * 512 + lane * 8, &Bs[S][(w * 2 + 0) * 512]);      \
    gload16(Bt + (w * 2 + 1) * 512 + lane * 8, &Bs[S][(w * 2 + 1) * 512]);      \
  }
#define QKV_ITER(KS, S)                                                         \
  {                                                                             \
    if ((KS) < 30)      asm volatile("s_waitcnt vmcnt(12)" ::: "memory");       \
    else if ((KS) == 30) asm volatile("s_waitcnt vmcnt(6)" ::: "memory");       \
    else                 asm volatile("s_waitcnt vmcnt(0)" ::: "memory");       \
    u32x4 w0 = {packh(ra[S][0][0], ra[S][0][1]), packh(ra[S][0][2], ra[S][0][3]),\
                packh(ra[S][1][0], ra[S][1][1]), packh(ra[S][1][2], ra[S][1][3])};\
    u32x4 w1 = {packh(ra[S][2][0], ra[S][2][1]), packh(ra[S][2][2], ra[S][2][3]),\
                packh(ra[S][3][0], ra[S][3][1]), packh(ra[S][3][2], ra[S][3][3])};\
    *(u32x4*)&As[S][aw0] = w0;                                                  \
    *(u32x4*)&As[S][aw1] = w1;                                                  \
    asm volatile("s_waitcnt lgkmcnt(0)" ::: "memory");                          \
    __builtin_amdgcn_s_barrier();                                               \
    __builtin_amdgcn_sched_barrier(0);                                          \
    f16x8 af[4], bfv[4];                                                        \
    _Pragma("unroll") for (int mi = 0; mi < 4; mi++) {                          \
      int row = wr * 64 + mi * 16 + fq;                                         \
      af[mi] = *(const f16x8*)&As[S][row * 32 + ((fc ^ ((row >> 1) & 3)) << 3)];\
    }                                                                           \
    _Pragma("unroll") for (int ni = 0; ni < 4; ni++) {                          \
      int row = wc * 64 + ni * 16 + fq;                                         \
      bfv[ni] = *(const f16x8*)&Bs[S][row * 32 + ((fc ^ ((row >> 1) & 3)) << 3)];\
    }                                                                           \
    __builtin_amdgcn_s_setprio(1);                                              \
    _Pragma("unroll") for (int mi = 0; mi < 4; mi++)                            \
      _Pragma("unroll") for (int ni = 0; ni < 4; ni++)                          \
        acc[mi][ni] =                                                           \
            __builtin_amdgcn_mfma_f32_16x16x32_f16(af[mi], bfv[ni], acc[mi][ni], 0, 0, 0); \
    __builtin_amdgcn_s_setprio(0);                                              \
    __builtin_amdgcn_sched_barrier(0);                                          \
    __builtin_amdgcn_s_barrier();                                               \
    if ((KS) < 29) { QKV_LOAD_A((KS) + 3, S); QKV_LOAD_B((KS) + 3, S); }        \
  }

  QKV_LOAD_A(0, 0); QKV_LOAD_B(0, 0);
  QKV_LOAD_A(1, 1); QKV_LOAD_B(1, 1);
  QKV_LOAD_A(2, 2); QKV_LOAD_B(2, 2);
  for (int kk3 = 0; kk3 < 10; kk3++) {
    QKV_ITER(kk3 * 3 + 0, 0);
    QKV_ITER(kk3 * 3 + 1, 1);
    QKV_ITER(kk3 * 3 + 2, 2);
  }
  QKV_ITER(30, 0);
  QKV_ITER(31, 1);
#undef QKV_LOAD_A
#undef QKV_LOAD_B
#undef QKV_ITER

  // -------- epilogue: stage C into SH in fragment order, then coalesced 16B stores ------
  __syncthreads();  // all waves done with As/Bs; SH reused as C tile
#pragma unroll
  for (int mi = 0; mi < 4; mi++)
#pragma unroll
    for (int ni = 0; ni < 4; ni++) {
      int n = n0 + wc * 64 + ni * 16 + fq;
      float bs = bias[n];
      int d_local = wc * 64 + ni * 16 + fq;
      int h_half = d_local >> 6, dd = d_local & 63;
#pragma unroll
      for (int r = 0; r < 4; r++) {
        int s_local = wr * 64 + mi * 16 + fc * 4 + r;
        float v = (acc[mi][ni][r] + bs) * scale;
        int cl, lp, e;
        if (vmode == 0) {
          cl = (s_local >> 4) * 2 + (dd >> 5);
          lp = ((dd & 31) >> 3) * 16 + (s_local & 15);
          e = dd & 7;
        } else {
          cl = (s_local >> 5) * 4 + (dd >> 4);
          lp = ((s_local & 31) >> 3) * 16 + (dd & 15);
          e = s_local & 7;
        }
        SH[h_half * 8192 + cl * 512 + lp * 8 + e] = f16r(v);
      }
    }
  __syncthreads();
  {
    int b = m0 >> 11, s_base = m0 & 2047;
    int h0 = n0 >> 6;  // two consecutive heads per tile
    u16* o0 = out + (size_t)(b * 16 + h0) * 131072 + (size_t)s_base * 64;
    u16* o1 = out + (size_t)(b * 16 + h0 + 1) * 131072 + (size_t)s_base * 64;
    int j0 = tid * 32;
#pragma unroll
    for (int i = 0; i < 4; i++)
      *(u32x4*)&o0[j0 + i * 8] = *(const u32x4*)&SH[j0 + i * 8];
#pragma unroll
    for (int i = 0; i < 4; i++)
      *(u32x4*)&o1[j0 + i * 8] = *(const u32x4*)&SH[8192 + j0 + i * 8];
  }
}

// ============ output GEMM: BK=64, 2-deep ring + counted vmcnt, single-product f16 ============
// A (ctx) pre-tiled kt64 (pc8 swizzle, written by attn); B (WoT) kt32 (pc4), 2 tiles/step.
__global__ __launch_bounds__(256) void gemm_o_k(
    const u16* __restrict__ Ag, const u16* __restrict__ Bg,
    const float* __restrict__ bias, float* __restrict__ out) {
  __shared__ u16 SA[2][8192];
  __shared__ u16 SB[2][8192];
  int lid = blockIdx.x;
  int xcd = lid & 7, idx = lid >> 3;
  int bx = idx & 7, by = xcd * 8 + (idx >> 3);
  int n0 = bx * 128, m0 = by * 128;
  int tid = threadIdx.x, lane = tid & 63;
  int w = tid >> 6, wr = w >> 1, wc = w & 1;
  int fq = lane & 15, fc = lane >> 4;
  f32x4 acc[4][4] = {};

  auto stage = [&](int ks, int sel) {
    size_t at = ((size_t)by * 16 + ks) * 8192;
    size_t bt = ((size_t)bx * 32 + ks * 2) * 4096;
#pragma unroll
    for (int i = 0; i < 4; i++) {
      int ub = (w * 4 + i) * 512;
      gload16(Ag + at + ub + lane * 8, &SA[sel][ub]);
      gload16(Bg + bt + ub + lane * 8, &SB[sel][ub]);
    }
  };

  stage(0, 0);
  stage(1, 1);
  for (int ks = 0; ks < 16; ks++) {
    int cur = ks & 1;
    if (ks < 15) asm volatile("s_waitcnt vmcnt(8)" ::: "memory");
    else         asm volatile("s_waitcnt vmcnt(0)" ::: "memory");
    __builtin_amdgcn_s_barrier();
    __builtin_amdgcn_sched_barrier(0);
#pragma unroll
    for (int kc = 0; kc < 2; kc++) {
      f16x8 ah[4], bh[4];
#pragma unroll
      for (int mi = 0; mi < 4; mi++) {
        int row = wr * 64 + mi * 16 + fq;
        ah[mi] = *(const f16x8*)&SA[cur][row * 64 + (((kc * 4 + fc) ^ (row & 7)) << 3)];
      }
#pragma unroll
      for (int ni = 0; ni < 4; ni++) {
        int row = wc * 64 + ni * 16 + fq;
        bh[ni] = *(const f16x8*)&SB[cur][kc * 4096 + row * 32 + (fc ^ ((row >> 1) & 3)) * 8];
      }
      __builtin_amdgcn_s_setprio(1);
#pragma unroll
      for (int mi = 0; mi < 4; mi++)
#pragma unroll
        for (int ni = 0; ni < 4; ni++)
          acc[mi][ni] = __builtin_amdgcn_mfma_f32_16x16x32_f16(ah[mi], bh[ni], acc[mi][ni], 0, 0, 0);
      __builtin_amdgcn_s_setprio(0);
    }
    __builtin_amdgcn_sched_barrier(0);
    __builtin_amdgcn_s_barrier();
    if (ks < 14) stage(ks + 2, cur);
  }
#pragma unroll
  for (int mi = 0; mi < 4; mi++)
#pragma unroll
    for (int ni = 0; ni < 4; ni++) {
      int n = n0 + wc * 64 + ni * 16 + fq;
      float bs = bias[n];
#pragma unroll
      for (int r = 0; r < 4; r++) {
        int m = m0 + wr * 64 + mi * 16 + fc * 4 + r;
        out[(size_t)m * 1024 + n] = acc[mi][ni][r] + bs;
      }
    }
}

// ============ flash attention v11: ones-MFMA l-sum + READER-LINEAR P layout ====
// P stored in the exact order PV's A-fragment read wants: P[w][ch*512 + lane*8] (lane*16B,
// conflict-free like K/V). Writer computes the inverse permutation per (sub, fc):
//   value kv=16s+4fc+r, q=fq  ->  reader lane fq+16*((2s+(fc>>1))&3), u32-slot 2*(fc&1).
__global__ __launch_bounds__(512) void attn_k(
    const u16* __restrict__ Q, const u16* __restrict__ Kg, const u16* __restrict__ Vg,
    u16* __restrict__ ctx) {
  int lid = blockIdx.x;
  int bh = (lid & 7) * 8 + (lid >> 6);  // XCD lid%8 owns bh in [xcd*8, xcd*8+8): K/V 4MB ~ one L2
  int qb = (lid >> 3) & 7;
  int tid = threadIdx.x, lane = tid & 63, w = tid >> 6;
  const u16* Qf = Q + (size_t)bh * 131072;
  const u16* Kf = Kg + (size_t)bh * 131072;
  const u16* Vf = Vg + (size_t)bh * 131072;
  int fq = lane & 15, fc = lane >> 4;
  int le = lane * 8;
  int q0 = qb * 256 + w * 32;

  __shared__ u16 KL[2][4096];
  __shared__ u16 VL[2][4096];
  __shared__ u16 P[8][1024];  // per wave: [ch(2)][lane(64)][8 f16] reader-linear

  f16x8 qf[2][2];
#pragma unroll
  for (int mi = 0; mi < 2; mi++)
#pragma unroll
    for (int kc = 0; kc < 2; kc++)
      qf[mi][kc] = *(const f16x8*)&Qf[((((q0 + 16 * mi) >> 4) * 2 + kc) << 9) + le];

  const f16x8 vones = {(_Float16)1.f, (_Float16)1.f, (_Float16)1.f, (_Float16)1.f,
                       (_Float16)1.f, (_Float16)1.f, (_Float16)1.f, (_Float16)1.f};
  f32x4 O[2][4] = {};
  f32x4 Ol[2] = {};  // l[q] via ones-MFMA; lane layout matches O rows (q = fc*4+r)

  // P writer address components (per-thread constants)
  int pslot = (fc & 1) * 4;   // u16 offset of this thread's u32x2 within the dest lane's 16B
  int pbase = fq + ((fc >> 1) << 4);  // dest lane before the 2s rotation

  // staging: waves 0-3 own K quarters, waves 4-7 own V quarters (2 gloads each)
  auto stage = [&](int tt, int bb) {
    int qo = (w & 3) * 1024;
    if (w < 4) {
      const u16* Kt = Kf + tt * 4096;
      gload16(Kt + qo + le, &KL[bb][qo]);
      gload16(Kt + qo + 512 + le, &KL[bb][qo + 512]);
    } else {
      const u16* Vt = Vf + tt * 4096;
      gload16(Vt + qo + le, &VL[bb][qo]);
      gload16(Vt + qo + 512 + le, &VL[bb][qo + 512]);
    }
  };

  stage(0, 0);
  stage(1, 1);
  for (int t = 0; t < 32; t++) {
    int buf = t & 1;
    if (t < 31) asm volatile("s_waitcnt vmcnt(2)" ::: "memory");
    else        asm volatile("s_waitcnt vmcnt(0)" ::: "memory");
    __builtin_amdgcn_s_barrier();
    __builtin_amdgcn_sched_barrier(0);

    f16x8 kf[8];
#pragma unroll
    for (int c = 0; c < 8; c++) kf[c] = *(const f16x8*)&KL[buf][c * 512 + le];

    f32x4 sc[2][4] = {};
    __builtin_amdgcn_s_setprio(1);
#pragma unroll
    for (int mi = 0; mi < 2; mi++)
#pragma unroll
      for (int sub = 0; sub < 4; sub++)
#pragma unroll
        for (int kc = 0; kc < 2; kc++)
          sc[mi][sub] = __builtin_amdgcn_mfma_f32_16x16x32_f16(kf[sub * 2 + kc], qf[mi][kc],
                                                               sc[mi][sub], 0, 0, 0);
    __builtin_amdgcn_s_setprio(0);

    f16x8 vf[8];
#pragma unroll
    for (int c = 0; c < 8; c++) vf[c] = *(const f16x8*)&VL[buf][c * 512 + le];

#pragma unroll
    for (int mi = 0; mi < 2; mi++) {
      // no-max softmax (log2-domain scores, bounded): exp2 + pack + scatter to reader-linear P
#pragma unroll
      for (int sub = 0; sub < 4; sub++) {
        float p0 = __builtin_amdgcn_exp2f(sc[mi][sub][0]);
        float p1 = __builtin_amdgcn_exp2f(sc[mi][sub][1]);
        float p2 = __builtin_amdgcn_exp2f(sc[mi][sub][2]);
        float p3 = __builtin_amdgcn_exp2f(sc[mi][sub][3]);
        u32x2 pw = {packh(p0, p1), packh(p2, p3)};
        int lp = (pbase + (sub << 5)) & 63;        // fq + 16*((2*sub + (fc>>1)) & 3)
        *(u32x2*)&P[w][(sub >> 1) * 512 + lp * 8 + pslot] = pw;
      }
      // PV + l-accumulation (compiler inserts precise lgkmcnt for the P round-trip)
      __builtin_amdgcn_s_setprio(1);
#pragma unroll
      for (int ch = 0; ch < 2; ch++) {
        f16x8 pa = *(const f16x8*)&P[w][ch * 512 + lane * 8];
        Ol[mi] = __builtin_amdgcn_mfma_f32_16x16x32_f16(pa, vones, Ol[mi], 0, 0, 0);
#pragma unroll
        for (int db = 0; db < 4; db++)
          O[mi][db] = __builtin_amdgcn_mfma_f32_16x16x32_f16(pa, vf[ch * 4 + db], O[mi][db], 0, 0, 0);
      }
      __builtin_amdgcn_s_setprio(0);
    }

    __builtin_amdgcn_sched_barrier(0);
    __builtin_amdgcn_s_barrier();  // all waves done reading buf
    if (t < 30) stage(t + 2, buf);
  }

  // finalize: /l (Ol lane layout == O lane layout: row q = fc*4+r), write ctx pre-tiled kt64/pc8
  int b = bh >> 4, h = bh & 15;
#pragma unroll
  for (int mi = 0; mi < 2; mi++) {
    float linv[4];
#pragma unroll
    for (int r = 0; r < 4; r++) linv[r] = 1.0f / Ol[mi][r];
#pragma unroll
    for (int db = 0; db < 4; db++)
#pragma unroll
      for (int r = 0; r < 4; r++) {
        float v = O[mi][db][r] * linv[r];
        int s = q0 + mi * 16 + fc * 4 + r;
        int mrow = s & 127, mt = b * 16 + (s >> 7);
        int lc = (db * 16 + fq) >> 3, e = fq & 7;
        int pc = lc ^ (mrow & 7);
        size_t o = ((size_t)(mt * 16 + h) * 128 + mrow) * 64 + pc * 8 + e;
        ctx[o] = f16r(v);
      }
  }
}

extern "C" void kernel_launch(void* const* d_in, const int* in_sizes, int n_in,
                              void* d_out, int out_size, void* d_ws, size_t ws_size,
                              hipStream_t stream) {
  const float* query = (const float*)d_in[0];
  const float* key   = (const float*)d_in[1];
  const float* value = (const float*)d_in[2];
  const float* Wq = (const float*)d_in[3];
  const float* bq = (const float*)d_in[4];
  const float* Wk = (const float*)d_in[5];
  const float* bk = (const float*)d_in[6];
  const float* Wv = (const float*)d_in[7];
  const float* bv = (const float*)d_in[8];
  const float* Wo = (const float*)d_in[9];
  const float* bo = (const float*)d_in[10];
  float* out = (float*)d_out;

  char* ws = (char*)d_ws;
  size_t off = 0;
  auto alloc = [&](size_t bytes) {
    char* p = ws + off;
    off += (bytes + 255) & ~(size_t)255;
    return p;
  };
  u16* WqT = (u16*)alloc(1048576 * 2);
  u16* WkT = (u16*)alloc(1048576 * 2);
  u16* WvT = (u16*)alloc(1048576 * 2);
  u16* WoT = (u16*)alloc(1048576 * 2);
  u16* Qbf = (u16*)alloc((size_t)8388608 * 2);
  u16* Kbf = (u16*)alloc((size_t)8388608 * 2);
  u16* ctx = (u16*)alloc((size_t)8388608 * 2);
  // V (fragment-ordered) lives in d_out temporarily; consumed by attn before gemm_o overwrites.
  u16* Vfb = (u16*)d_out;

  const float QSCALE = 0.125f * 1.44269504f;  // 1/sqrt(hd) * log2(e) folded into Q

  wtrans4_k<<<dim3(32, 32, 4), 256, 0, stream>>>(Wq, Wk, Wv, Wo, WqT, WkT, WvT, WoT);
  gemm_qkv_k<<<dim3(512, 1, 3), 256, 0, stream>>>(query, key, value, WqT, WkT, WvT,
                                                  bq, bk, bv, Qbf, Kbf, Vfb, QSCALE);
  attn_k<<<512, 512, 0, stream>>>(Qbf, Kbf, Vfb, ctx);
  gemm_o_k<<<512, 256, 0, stream>>>(ctx, WoT, bo, out);
}

// Round 22
// 183.869 us; speedup vs baseline: 1.0509x; 1.0509x over previous
//
#include <hip/hip_runtime.h>

typedef unsigned short u16;
typedef unsigned int u32;
typedef _Float16 f16;
typedef __attribute__((ext_vector_type(8))) _Float16 f16x8;
typedef __attribute__((ext_vector_type(4))) float f32x4;
typedef __attribute__((ext_vector_type(4))) u32 u32x4;
typedef __attribute__((ext_vector_type(2))) u32 u32x2;
typedef __attribute__((ext_vector_type(4))) u16 u16x4;

static __device__ __forceinline__ u16 f16r(float f) {  // RNE f32->f16 bits
  return __builtin_bit_cast(u16, (_Float16)f);
}
static __device__ __forceinline__ u32 packh(float a, float b) {  // v_cvt_pkrtz_f16_f32
  return __builtin_bit_cast(u32, __builtin_amdgcn_cvt_pkrtz(a, b));
}
// async global->LDS, 16B/lane; LDS dst = wave-uniform base + lane*16 (HW), global src per-lane
static __device__ __forceinline__ void gload16(const u16* g, u16* l) {
  __builtin_amdgcn_global_load_lds((const __attribute__((address_space(1))) void*)g,
                                   (__attribute__((address_space(3))) void*)l, 16, 0, 0);
}

// ============ fused weight transpose: W[k][n] fp32 -> pre-tiled/swizzled f16 ============
// WT layout: [nt(8)][kt32(32)][row(128)][pc(4)][8 u16], pc = lc ^ ((row>>1)&3), lc = (k&31)>>3
__global__ __launch_bounds__(256) void wtrans4_k(
    const float* __restrict__ Wq, const float* __restrict__ Wk,
    const float* __restrict__ Wv, const float* __restrict__ Wo,
    u16* __restrict__ Tq, u16* __restrict__ Tk, u16* __restrict__ Tv, u16* __restrict__ To) {
  int z = blockIdx.z;
  const float* W = z == 0 ? Wq : z == 1 ? Wk : z == 2 ? Wv : Wo;
  u16* WT = z == 0 ? Tq : z == 1 ? Tk : z == 2 ? Tv : To;
  __shared__ float tile[32][33];
  int k0 = blockIdx.x * 32, n0 = blockIdx.y * 32;
  int t = threadIdx.x;
  int r = t >> 3, c = (t & 7) * 4;
  f32x4 v = *(const f32x4*)&W[(size_t)(k0 + r) * 1024 + n0 + c];
  tile[r][c + 0] = v[0]; tile[r][c + 1] = v[1]; tile[r][c + 2] = v[2]; tile[r][c + 3] = v[3];
  __syncthreads();
  int n = n0 + (t >> 3), kbase = k0 + (t & 7) * 4;
  u16x4 o;
#pragma unroll
  for (int j = 0; j < 4; j++) o[j] = f16r(tile[(t & 7) * 4 + j][t >> 3]);
  int nt = n >> 7, row = n & 127;
  int kt = kbase >> 5, lc = (kbase >> 3) & 3, e = kbase & 7;
  int pc = lc ^ ((row >> 1) & 3);
  *(u16x4*)&WT[((size_t)(nt * 32 + kt) * 128 + row) * 32 + pc * 8 + e] = o;
}

// ============ fused Q/K/V projection GEMM: BK=32, 2-deep ring, REG-STAGED f16 A ====
// A: plain f32x4 loads -> cvt_pkrtz -> ds_write f16 As (8KB/buf); B: linear gload_lds.
// Epilogue: LDS-bounce — C tile staged fragment-ordered in the (aliased) 32KB shared
// buffer, then written as two contiguous 16KB runs with 16B coalesced stores.
__global__ __launch_bounds__(256) void gemm_qkv_k(
    const float* __restrict__ Aq, const float* __restrict__ Ak, const float* __restrict__ Av,
    const u16* __restrict__ Tq, const u16* __restrict__ Tk, const u16* __restrict__ Tv,
    const float* __restrict__ bq, const float* __restrict__ bk, const float* __restrict__ bv,
    u16* __restrict__ Qo, u16* __restrict__ Ko, u16* __restrict__ Vo, float qscale) {
  int z = blockIdx.z;
  const float* A = z == 0 ? Aq : z == 1 ? Ak : Av;
  const u16* BT = z == 0 ? Tq : z == 1 ? Tk : Tv;
  const float* bias = z == 0 ? bq : z == 1 ? bk : bv;
  u16* out = z == 0 ? Qo : z == 1 ? Ko : Vo;
  int vmode = (z == 2);
  float scale = z == 0 ? qscale : 1.0f;

  __shared__ u16 SH[16384];  // As[2][4096] | Bs[2][4096] during K-loop; C tile in epilogue
  u16 (*As)[4096] = (u16(*)[4096])SH;
  u16 (*Bs)[4096] = (u16(*)[4096])(SH + 8192);
  int lid = blockIdx.x;
  int xcd = lid & 7, idx = lid >> 3;
  int bx = idx & 7, by = xcd * 8 + (idx >> 3);
  int n0 = bx * 128, m0 = by * 128;
  int tid = threadIdx.x, lane = tid & 63;
  int w = tid >> 6, wr = w >> 1, wc = w & 1;
  int fq = lane & 15, fc = lane >> 4;
  f32x4 acc[4][4] = {};
  const u16* BTb = BT + (size_t)bx * 131072;
  const float* Ab = A + (size_t)m0 * 1024;

  // A staging geometry: unit = (row, lc); thread handles (arow0, lc) and (arow0+64, lc)
  int arow0 = tid >> 2;          // 0..63
  int arow1 = arow0 + 64;
  int acol = (tid & 3) * 8;      // float col within the 32-float K slab
  int apc = (tid & 3) ^ ((arow0 >> 1) & 3);  // same for arow1 (+64 preserves (row>>1)&3)
  int aw0 = arow0 * 32 + apc * 8;
  int aw1 = arow1 * 32 + apc * 8;
  f32x4 ra[2][4];

#define QKV_LOAD_A(KS, S)                                                       \
  {                                                                             \
    const float* Ap = Ab + (KS) * 32 + acol;                                    \
    ra[S][0] = *(const f32x4*)(Ap + (size_t)arow0 * 1024);                      \
    ra[S][1] = *(const f32x4*)(Ap + (size_t)arow0 * 1024 + 4);                  \
    ra[S][2] = *(const f32x4*)(Ap + (size_t)arow1 * 1024);                      \
    ra[S][3] = *(const f32x4*)(Ap + (size_t)arow1 * 1024 + 4);                  \
  }
#define QKV_LOAD_B(KS, S)                                                       \
  {                                                                             \
    const u16* Bt = BTb + (KS) * 4096;                                          \
    gload16(Bt + (w * 2 + 0) * 512 + lane * 8, &Bs[S][(w * 2 + 0) * 512]);      \
    gload16(Bt + (w * 2 + 1) * 512 + lane * 8, &Bs[S][(w * 2 + 1) * 512]);      \
  }
#define QKV_ITER(KS, S)                                                         \
  {                                                                             \
    if ((KS) < 31) asm volatile("s_waitcnt vmcnt(6)" ::: "memory");             \
    else           asm volatile("s_waitcnt vmcnt(0)" ::: "memory");             \
    u32x4 w0 = {packh(ra[S][0][0], ra[S][0][1]), packh(ra[S][0][2], ra[S][0][3]),\
                packh(ra[S][1][0], ra[S][1][1]), packh(ra[S][1][2], ra[S][1][3])};\
    u32x4 w1 = {packh(ra[S][2][0], ra[S][2][1]), packh(ra[S][2][2], ra[S][2][3]),\
                packh(ra[S][3][0], ra[S][3][1]), packh(ra[S][3][2], ra[S][3][3])};\
    *(u32x4*)&As[S][aw0] = w0;                                                  \
    *(u32x4*)&As[S][aw1] = w1;                                                  \
    asm volatile("s_waitcnt lgkmcnt(0)" ::: "memory");                          \
    __builtin_amdgcn_s_barrier();                                               \
    __builtin_amdgcn_sched_barrier(0);                                          \
    f16x8 af[4], bfv[4];                                                        \
    _Pragma("unroll") for (int mi = 0; mi < 4; mi++) {                          \
      int row = wr * 64 + mi * 16 + fq;                                         \
      af[mi] = *(const f16x8*)&As[S][row * 32 + ((fc ^ ((row >> 1) & 3)) << 3)];\
    }                                                                           \
    _Pragma("unroll") for (int ni = 0; ni < 4; ni++) {                          \
      int row = wc * 64 + ni * 16 + fq;                                         \
      bfv[ni] = *(const f16x8*)&Bs[S][row * 32 + ((fc ^ ((row >> 1) & 3)) << 3)];\
    }                                                                           \
    __builtin_amdgcn_s_setprio(1);                                              \
    _Pragma("unroll") for (int mi = 0; mi < 4; mi++)                            \
      _Pragma("unroll") for (int ni = 0; ni < 4; ni++)                          \
        acc[mi][ni] =                                                           \
            __builtin_amdgcn_mfma_f32_16x16x32_f16(af[mi], bfv[ni], acc[mi][ni], 0, 0, 0); \
    __builtin_amdgcn_s_setprio(0);                                              \
    __builtin_amdgcn_sched_barrier(0);                                          \
    __builtin_amdgcn_s_barrier();                                               \
    if ((KS) < 30) { QKV_LOAD_A((KS) + 2, S); QKV_LOAD_B((KS) + 2, S); }        \
  }

  QKV_LOAD_A(0, 0); QKV_LOAD_B(0, 0);
  QKV_LOAD_A(1, 1); QKV_LOAD_B(1, 1);
  for (int kk2 = 0; kk2 < 16; kk2++) {
    QKV_ITER(kk2 * 2, 0);
    QKV_ITER(kk2 * 2 + 1, 1);
  }
#undef QKV_LOAD_A
#undef QKV_LOAD_B
#undef QKV_ITER

  // -------- epilogue: stage C into SH in fragment order, then coalesced 16B stores ------
  __syncthreads();  // all waves done with As/Bs; SH reused as C tile
#pragma unroll
  for (int mi = 0; mi < 4; mi++)
#pragma unroll
    for (int ni = 0; ni < 4; ni++) {
      int n = n0 + wc * 64 + ni * 16 + fq;
      float bs = bias[n];
      int d_local = wc * 64 + ni * 16 + fq;
      int h_half = d_local >> 6, dd = d_local & 63;
#pragma unroll
      for (int r = 0; r < 4; r++) {
        int s_local = wr * 64 + mi * 16 + fc * 4 + r;
        float v = (acc[mi][ni][r] + bs) * scale;
        int cl, lp, e;
        if (vmode == 0) {
          cl = (s_local >> 4) * 2 + (dd >> 5);
          lp = ((dd & 31) >> 3) * 16 + (s_local & 15);
          e = dd & 7;
        } else {
          cl = (s_local >> 5) * 4 + (dd >> 4);
          lp = ((s_local & 31) >> 3) * 16 + (dd & 15);
          e = s_local & 7;
        }
        SH[h_half * 8192 + cl * 512 + lp * 8 + e] = f16r(v);
      }
    }
  __syncthreads();
  {
    int b = m0 >> 11, s_base = m0 & 2047;
    int h0 = n0 >> 6;  // two consecutive heads per tile
    u16* o0 = out + (size_t)(b * 16 + h0) * 131072 + (size_t)s_base * 64;
    u16* o1 = out + (size_t)(b * 16 + h0 + 1) * 131072 + (size_t)s_base * 64;
    int j0 = tid * 32;
#pragma unroll
    for (int i = 0; i < 4; i++)
      *(u32x4*)&o0[j0 + i * 8] = *(const u32x4*)&SH[j0 + i * 8];
#pragma unroll
    for (int i = 0; i < 4; i++)
      *(u32x4*)&o1[j0 + i * 8] = *(const u32x4*)&SH[8192 + j0 + i * 8];
  }
}

// ============ output GEMM: BK=64, 2-deep ring + counted vmcnt, single-product f16 ============
// A (ctx) pre-tiled kt64 (pc8 swizzle, written by attn); B (WoT) kt32 (pc4), 2 tiles/step.
__global__ __launch_bounds__(256) void gemm_o_k(
    const u16* __restrict__ Ag, const u16* __restrict__ Bg,
    const float* __restrict__ bias, float* __restrict__ out) {
  __shared__ u16 SA[2][8192];
  __shared__ u16 SB[2][8192];
  int lid = blockIdx.x;
  int xcd = lid & 7, idx = lid >> 3;
  int bx = idx & 7, by = xcd * 8 + (idx >> 3);
  int n0 = bx * 128, m0 = by * 128;
  int tid = threadIdx.x, lane = tid & 63;
  int w = tid >> 6, wr = w >> 1, wc = w & 1;
  int fq = lane & 15, fc = lane >> 4;
  f32x4 acc[4][4] = {};

  auto stage = [&](int ks, int sel) {
    size_t at = ((size_t)by * 16 + ks) * 8192;
    size_t bt = ((size_t)bx * 32 + ks * 2) * 4096;
#pragma unroll
    for (int i = 0; i < 4; i++) {
      int ub = (w * 4 + i) * 512;
      gload16(Ag + at + ub + lane * 8, &SA[sel][ub]);
      gload16(Bg + bt + ub + lane * 8, &SB[sel][ub]);
    }
  };

  stage(0, 0);
  stage(1, 1);
  for (int ks = 0; ks < 16; ks++) {
    int cur = ks & 1;
    if (ks < 15) asm volatile("s_waitcnt vmcnt(8)" ::: "memory");
    else         asm volatile("s_waitcnt vmcnt(0)" ::: "memory");
    __builtin_amdgcn_s_barrier();
    __builtin_amdgcn_sched_barrier(0);
#pragma unroll
    for (int kc = 0; kc < 2; kc++) {
      f16x8 ah[4], bh[4];
#pragma unroll
      for (int mi = 0; mi < 4; mi++) {
        int row = wr * 64 + mi * 16 + fq;
        ah[mi] = *(const f16x8*)&SA[cur][row * 64 + (((kc * 4 + fc) ^ (row & 7)) << 3)];
      }
#pragma unroll
      for (int ni = 0; ni < 4; ni++) {
        int row = wc * 64 + ni * 16 + fq;
        bh[ni] = *(const f16x8*)&SB[cur][kc * 4096 + row * 32 + (fc ^ ((row >> 1) & 3)) * 8];
      }
      __builtin_amdgcn_s_setprio(1);
#pragma unroll
      for (int mi = 0; mi < 4; mi++)
#pragma unroll
        for (int ni = 0; ni < 4; ni++)
          acc[mi][ni] = __builtin_amdgcn_mfma_f32_16x16x32_f16(ah[mi], bh[ni], acc[mi][ni], 0, 0, 0);
      __builtin_amdgcn_s_setprio(0);
    }
    __builtin_amdgcn_sched_barrier(0);
    __builtin_amdgcn_s_barrier();
    if (ks < 14) stage(ks + 2, cur);
  }
#pragma unroll
  for (int mi = 0; mi < 4; mi++)
#pragma unroll
    for (int ni = 0; ni < 4; ni++) {
      int n = n0 + wc * 64 + ni * 16 + fq;
      float bs = bias[n];
#pragma unroll
      for (int r = 0; r < 4; r++) {
        int m = m0 + wr * 64 + mi * 16 + fc * 4 + r;
        out[(size_t)m * 1024 + n] = acc[mi][ni][r] + bs;
      }
    }
}

// ============ flash attention v11: ones-MFMA l-sum + READER-LINEAR P layout ====
// P stored in the exact order PV's A-fragment read wants: P[w][ch*512 + lane*8] (lane*16B,
// conflict-free like K/V). Writer computes the inverse permutation per (sub, fc):
//   value kv=16s+4fc+r, q=fq  ->  reader lane fq+16*((2s+(fc>>1))&3), u32-slot 2*(fc&1).
__global__ __launch_bounds__(512) void attn_k(
    const u16* __restrict__ Q, const u16* __restrict__ Kg, const u16* __restrict__ Vg,
    u16* __restrict__ ctx) {
  int lid = blockIdx.x;
  int bh = (lid & 7) * 8 + (lid >> 6);  // XCD lid%8 owns bh in [xcd*8, xcd*8+8): K/V 4MB ~ one L2
  int qb = (lid >> 3) & 7;
  int tid = threadIdx.x, lane = tid & 63, w = tid >> 6;
  const u16* Qf = Q + (size_t)bh * 131072;
  const u16* Kf = Kg + (size_t)bh * 131072;
  const u16* Vf = Vg + (size_t)bh * 131072;
  int fq = lane & 15, fc = lane >> 4;
  int le = lane * 8;
  int q0 = qb * 256 + w * 32;

  __shared__ u16 KL[2][4096];
  __shared__ u16 VL[2][4096];
  __shared__ u16 P[8][1024];  // per wave: [ch(2)][lane(64)][8 f16] reader-linear

  f16x8 qf[2][2];
#pragma unroll
  for (int mi = 0; mi < 2; mi++)
#pragma unroll
    for (int kc = 0; kc < 2; kc++)
      qf[mi][kc] = *(const f16x8*)&Qf[((((q0 + 16 * mi) >> 4) * 2 + kc) << 9) + le];

  const f16x8 vones = {(_Float16)1.f, (_Float16)1.f, (_Float16)1.f, (_Float16)1.f,
                       (_Float16)1.f, (_Float16)1.f, (_Float16)1.f, (_Float16)1.f};
  f32x4 O[2][4] = {};
  f32x4 Ol[2] = {};  // l[q] via ones-MFMA; lane layout matches O rows (q = fc*4+r)

  // P writer address components (per-thread constants)
  int pslot = (fc & 1) * 4;   // u16 offset of this thread's u32x2 within the dest lane's 16B
  int pbase = fq + ((fc >> 1) << 4);  // dest lane before the 2s rotation

  // staging: waves 0-3 own K quarters, waves 4-7 own V quarters (2 gloads each)
  auto stage = [&](int tt, int bb) {
    int qo = (w & 3) * 1024;
    if (w < 4) {
      const u16* Kt = Kf + tt * 4096;
      gload16(Kt + qo + le, &KL[bb][qo]);
      gload16(Kt + qo + 512 + le, &KL[bb][qo + 512]);
    } else {
      const u16* Vt = Vf + tt * 4096;
      gload16(Vt + qo + le, &VL[bb][qo]);
      gload16(Vt + qo + 512 + le, &VL[bb][qo + 512]);
    }
  };

  stage(0, 0);
  stage(1, 1);
  for (int t = 0; t < 32; t++) {
    int buf = t & 1;
    if (t < 31) asm volatile("s_waitcnt vmcnt(2)" ::: "memory");
    else        asm volatile("s_waitcnt vmcnt(0)" ::: "memory");
    __builtin_amdgcn_s_barrier();
    __builtin_amdgcn_sched_barrier(0);

    f16x8 kf[8];
#pragma unroll
    for (int c = 0; c < 8; c++) kf[c] = *(const f16x8*)&KL[buf][c * 512 + le];

    f32x4 sc[2][4] = {};
    __builtin_amdgcn_s_setprio(1);
#pragma unroll
    for (int mi = 0; mi < 2; mi++)
#pragma unroll
      for (int sub = 0; sub < 4; sub++)
#pragma unroll
        for (int kc = 0; kc < 2; kc++)
          sc[mi][sub] = __builtin_amdgcn_mfma_f32_16x16x32_f16(kf[sub * 2 + kc], qf[mi][kc],
                                                               sc[mi][sub], 0, 0, 0);
    __builtin_amdgcn_s_setprio(0);

    f16x8 vf[8];
#pragma unroll
    for (int c = 0; c < 8; c++) vf[c] = *(const f16x8*)&VL[buf][c * 512 + le];

#pragma unroll
    for (int mi = 0; mi < 2; mi++) {
      // no-max softmax (log2-domain scores, bounded): exp2 + pack + scatter to reader-linear P
#pragma unroll
      for (int sub = 0; sub < 4; sub++) {
        float p0 = __builtin_amdgcn_exp2f(sc[mi][sub][0]);
        float p1 = __builtin_amdgcn_exp2f(sc[mi][sub][1]);
        float p2 = __builtin_amdgcn_exp2f(sc[mi][sub][2]);
        float p3 = __builtin_amdgcn_exp2f(sc[mi][sub][3]);
        u32x2 pw = {packh(p0, p1), packh(p2, p3)};
        int lp = (pbase + (sub << 5)) & 63;        // fq + 16*((2*sub + (fc>>1)) & 3)
        *(u32x2*)&P[w][(sub >> 1) * 512 + lp * 8 + pslot] = pw;
      }
      // PV + l-accumulation (compiler inserts precise lgkmcnt for the P round-trip)
      __builtin_amdgcn_s_setprio(1);
#pragma unroll
      for (int ch = 0; ch < 2; ch++) {
        f16x8 pa = *(const f16x8*)&P[w][ch * 512 + lane * 8];
        Ol[mi] = __builtin_amdgcn_mfma_f32_16x16x32_f16(pa, vones, Ol[mi], 0, 0, 0);
#pragma unroll
        for (int db = 0; db < 4; db++)
          O[mi][db] = __builtin_amdgcn_mfma_f32_16x16x32_f16(pa, vf[ch * 4 + db], O[mi][db], 0, 0, 0);
      }
      __builtin_amdgcn_s_setprio(0);
    }

    __builtin_amdgcn_sched_barrier(0);
    __builtin_amdgcn_s_barrier();  // all waves done reading buf
    if (t < 30) stage(t + 2, buf);
  }

  // finalize: /l (Ol lane layout == O lane layout: row q = fc*4+r), write ctx pre-tiled kt64/pc8
  int b = bh >> 4, h = bh & 15;
#pragma unroll
  for (int mi = 0; mi < 2; mi++) {
    float linv[4];
#pragma unroll
    for (int r = 0; r < 4; r++) linv[r] = 1.0f / Ol[mi][r];
#pragma unroll
    for (int db = 0; db < 4; db++)
#pragma unroll
      for (int r = 0; r < 4; r++) {
        float v = O[mi][db][r] * linv[r];
        int s = q0 + mi * 16 + fc * 4 + r;
        int mrow = s & 127, mt = b * 16 + (s >> 7);
        int lc = (db * 16 + fq) >> 3, e = fq & 7;
        int pc = lc ^ (mrow & 7);
        size_t o = ((size_t)(mt * 16 + h) * 128 + mrow) * 64 + pc * 8 + e;
        ctx[o] = f16r(v);
      }
  }
}

extern "C" void kernel_launch(void* const* d_in, const int* in_sizes, int n_in,
                              void* d_out, int out_size, void* d_ws, size_t ws_size,
                              hipStream_t stream) {
  const float* query = (const float*)d_in[0];
  const float* key   = (const float*)d_in[1];
  const float* value = (const float*)d_in[2];
  const float* Wq = (const float*)d_in[3];
  const float* bq = (const float*)d_in[4];
  const float* Wk = (const float*)d_in[5];
  const float* bk = (const float*)d_in[6];
  const float* Wv = (const float*)d_in[7];
  const float* bv = (const float*)d_in[8];
  const float* Wo = (const float*)d_in[9];
  const float* bo = (const float*)d_in[10];
  float* out = (float*)d_out;

  char* ws = (char*)d_ws;
  size_t off = 0;
  auto alloc = [&](size_t bytes) {
    char* p = ws + off;
    off += (bytes + 255) & ~(size_t)255;
    return p;
  };
  u16* WqT = (u16*)alloc(1048576 * 2);
  u16* WkT = (u16*)alloc(1048576 * 2);
  u16* WvT = (u16*)alloc(1048576 * 2);
  u16* WoT = (u16*)alloc(1048576 * 2);
  u16* Qbf = (u16*)alloc((size_t)8388608 * 2);
  u16* Kbf = (u16*)alloc((size_t)8388608 * 2);
  u16* ctx = (u16*)alloc((size_t)8388608 * 2);
  // V (fragment-ordered) lives in d_out temporarily; consumed by attn before gemm_o overwrites.
  u16* Vfb = (u16*)d_out;

  const float QSCALE = 0.125f * 1.44269504f;  // 1/sqrt(hd) * log2(e) folded into Q

  wtrans4_k<<<dim3(32, 32, 4), 256, 0, stream>>>(Wq, Wk, Wv, Wo, WqT, WkT, WvT, WoT);
  gemm_qkv_k<<<dim3(512, 1, 3), 256, 0, stream>>>(query, key, value, WqT, WkT, WvT,
                                                  bq, bk, bv, Qbf, Kbf, Vfb, QSCALE);
  attn_k<<<512, 512, 0, stream>>>(Qbf, Kbf, Vfb, ctx);
  gemm_o_k<<<512, 256, 0, stream>>>(ctx, WoT, bo, out);
}